// Round 7
// baseline (151.242 us; speedup 1.0000x reference)
//
#include <hip/hip_runtime.h>
#include <hip/hip_fp16.h>

// Problem constants (B,S,H,N_IN,N_PROC,R) = (4,1024,1024,64,16,128)
#define T_TOK 4096   // B*S tokens
#define H_DIM 1024
#define NIN   64
#define NP    16
#define R_DIM 128
#define S_DIM 1024
#define N1    (NP * R_DIM)   // 2048

typedef _Float16 half8  __attribute__((ext_vector_type(8)));
typedef _Float16 half4v __attribute__((ext_vector_type(4)));
typedef float    floatx16 __attribute__((ext_vector_type(16)));

typedef __attribute__((address_space(3))) unsigned char lds_u8_t;
typedef __attribute__((address_space(1))) unsigned char gbl_u8_t;

// async global->LDS, 16B/lane; LDS base must be wave-uniform (HW: base + lane*16)
__device__ __forceinline__ void g2l16(const void* g, void* l) {
  __builtin_amdgcn_global_load_lds((const gbl_u8_t*)g, (lds_u8_t*)l, 16, 0, 0);
}

// ---------------- MFMA GEMM: C(MxN) = A(MxK) * BT(NxK)^T --------------------
// BK=128 (256B LDS rows = 16 x 16B chunks), 2x2 waves, 32x32x16 f16 MFMA.
// XOR swizzle (R6-verified: SQ_LDS_BANK_CONFLICT == 0): staging lane (rl, ql)
// fetches logical chunk ql^(row&15); read side p = (2h+kh)^(r&15).
// R7: smaller tiles for occupancy — GEMM2 was latency-bound at 2 blocks/CU
// (MfmaUtil 12%, all pipes idle). GEMM1 64x128 -> 3 blk/CU, GEMM2 64x64 -> 4.
template <int BM, int BN, int GATE, int K, int N>
__global__ __launch_bounds__(256)
void gemm_kernel(const _Float16* __restrict__ A, const _Float16* __restrict__ BT,
                 const float* __restrict__ gv, void* __restrict__ Cv) {
  constexpr int BK = 128, NCH = BK / 8;       // 16 chunks of 16B per row
  constexpr int RPC = 64 / NCH;               // 4 rows per 1KB staging call
  constexpr int WM = BM / 2, WN = BN / 2;
  constexpr int MI = WM / 32, NJ = WN / 32;
  constexpr int CA = BM * BK / 2048, CB = BN * BK / 2048;  // calls/wave
  __shared__ __align__(16) char smem[(BM + BN) * BK * 2];
  _Float16* sA = (_Float16*)smem;
  _Float16* sB = (_Float16*)(smem + (size_t)BM * BK * 2);

  const int tid = threadIdx.x, wave = tid >> 6, lane = tid & 63;
  const int bxi = blockIdx.x, byi = blockIdx.y;
  const int m0 = byi * BM, n0 = bxi * BN;
  const int wr = (wave >> 1) * WM, wc = (wave & 1) * WN;
  const int rl = lane >> 4;            // staging: row within 4-row call
  const int ql = lane & 15;            // staging: physical chunk position
  const int r = lane & 31, kh = lane >> 5;

  floatx16 acc[MI][NJ];
  #pragma unroll
  for (int i = 0; i < MI; ++i)
    #pragma unroll
    for (int j = 0; j < NJ; ++j) acc[i][j] = (floatx16)0.f;

  #pragma unroll
  for (int k0 = 0; k0 < K; k0 += BK) {
    __syncthreads();
    #pragma unroll
    for (int c = 0; c < CA; ++c) {
      const int rowB = wave * CA * RPC + c * RPC;    // wave-uniform call base
      const int rowL = rowB + rl;                    // this lane's row
      const int q = ql ^ (rowL & (NCH - 1));
      g2l16(A + (size_t)(m0 + rowL) * K + k0 + q * 8, sA + (size_t)rowB * BK);
    }
    #pragma unroll
    for (int c = 0; c < CB; ++c) {
      const int rowB = wave * CB * RPC + c * RPC;
      const int rowL = rowB + rl;
      const int q = ql ^ (rowL & (NCH - 1));
      g2l16(BT + (size_t)(n0 + rowL) * K + k0 + q * 8, sB + (size_t)rowB * BK);
    }
    __syncthreads();
    #pragma unroll
    for (int h = 0; h < BK / 16; ++h) {
      const int p8 = ((2 * h + kh) ^ (r & (NCH - 1))) * 8;  // swizzled 16B slot
      half8 af[MI], bf[NJ];
      #pragma unroll
      for (int i = 0; i < MI; ++i)
        af[i] = *reinterpret_cast<const half8*>(&sA[(wr + i * 32 + r) * BK + p8]);
      #pragma unroll
      for (int j = 0; j < NJ; ++j)
        bf[j] = *reinterpret_cast<const half8*>(&sB[(wc + j * 32 + r) * BK + p8]);
      #pragma unroll
      for (int i = 0; i < MI; ++i)
        #pragma unroll
        for (int j = 0; j < NJ; ++j)
          acc[i][j] = __builtin_amdgcn_mfma_f32_32x32x16_f16(af[i], bf[j], acc[i][j], 0, 0, 0);
    }
  }

  // 32x32 C/D layout: col = lane&31, row = (reg&3) + 8*(reg>>2) + 4*kh
  if (GATE) {
    _Float16* C = (_Float16*)Cv;   // BN==128 -> bxi == neuron n
    #pragma unroll
    for (int i = 0; i < MI; ++i)
      #pragma unroll
      for (int g4 = 0; g4 < 4; ++g4)
        #pragma unroll
        for (int rr = 0; rr < 4; ++rr) {
          const int rowL = wr + i * 32 + rr + 8 * g4 + 4 * kh;
          const float g = gv[(size_t)(m0 + rowL) * NP + bxi];  // L1-hot
          #pragma unroll
          for (int j = 0; j < NJ; ++j)
            C[(size_t)(m0 + rowL) * N + n0 + wc + j * 32 + r] =
                (_Float16)(acc[i][j][g4 * 4 + rr] * g);
        }
  } else {
    float* C = (float*)Cv;
    #pragma unroll
    for (int i = 0; i < MI; ++i)
      #pragma unroll
      for (int g4 = 0; g4 < 4; ++g4)
        #pragma unroll
        for (int rr = 0; rr < 4; ++rr) {
          const int rowL = wr + i * 32 + rr + 8 * g4 + 4 * kh;
          #pragma unroll
          for (int j = 0; j < NJ; ++j)
            C[(size_t)(m0 + rowL) * N + n0 + wc + j * 32 + r] = acc[i][j][g4 * 4 + rr];
        }
  }
}

// ---------------- prep: gates + cast + 2 transposes, ONE dispatch -----------
__global__ __launch_bounds__(256)
void prep_kernel(const float* __restrict__ enr, const float* __restrict__ cw,
                 const float* __restrict__ cb, const float* __restrict__ inter,
                 const float* __restrict__ dproj, const float* __restrict__ uproj,
                 float* __restrict__ gates, _Float16* __restrict__ Xh,
                 _Float16* __restrict__ BT1, _Float16* __restrict__ UT) {
  __shared__ __align__(16) char smem[25664];
  const int tid = threadIdx.x;
  const int bx = blockIdx.x, nb = gridDim.x;
  // ---- cast X fp32->fp16, grid-stride over 1M float4
  {
    const float4* src = (const float4*)inter;
    half4v* dst = (half4v*)Xh;
    for (int i = bx * 256 + tid; i < T_TOK * H_DIM / 4; i += nb * 256) {
      float4 v = src[i];
      half4v o;
      o[0] = (_Float16)v.x; o[1] = (_Float16)v.y; o[2] = (_Float16)v.z; o[3] = (_Float16)v.w;
      dst[i] = o;
    }
  }
  // ---- gates conv(k=5, 64ch mix)+sigmoid, blocks 0..255, 16 tokens each
  if (bx < 256) {
    float (*sw)[321] = (float (*)[321])smem;            // 20544 B
    float (*se)[NIN] = (float (*)[NIN])(smem + 20544);  //  5120 B
    const int t0 = bx * 16;
    const int b = t0 >> 10, s0 = t0 & 1023;   // 16 | S: no batch straddle
    for (int i = tid; i < NP * 320; i += 256) sw[i / 320][i % 320] = cw[i];
    for (int i = tid; i < 20 * NIN; i += 256) {
      int rr = i >> 6, c = i & 63, s = s0 + rr - 2;
      se[rr][c] = (s >= 0 && s < S_DIM) ? enr[((size_t)b * S_DIM + s) * NIN + c] : 0.f;
    }
    __syncthreads();
    const int lt = tid >> 4, n = tid & 15;
    float acc = cb[n];
    #pragma unroll
    for (int dh = 0; dh < 5; ++dh) {
      const float* wrow = &sw[n][dh * 64];
      const float* erow = se[lt + dh];
      #pragma unroll
      for (int j = 0; j < NIN; ++j) acc += erow[j] * wrow[j];
    }
    gates[(size_t)(t0 + lt) * NP + n] = 1.f / (1.f + expf(-acc));
    __syncthreads();   // LDS reused by transposes next
  }
  // ---- transpose+cast units (2048 dprojT + 2048 uprojT), strided over grid
  for (int u = bx; u < 4096; u += nb) {
    const float* src; _Float16* dst; int rows, cols, bxt, byt;
    if (u < 2048) {      // dproj[n] (1024x128) -> BT1 block n (128x1024)
      int n = u >> 7, rem = u & 127;
      src = dproj + (size_t)n * H_DIM * R_DIM;
      dst = BT1 + (size_t)n * R_DIM * H_DIM;
      rows = H_DIM; cols = R_DIM; bxt = rem & 3; byt = rem >> 2;
    } else {             // uproj (2048x1024) -> UT (1024x2048)
      int u2 = u - 2048;
      src = uproj; dst = UT; rows = N1; cols = H_DIM;
      bxt = u2 & 31; byt = u2 >> 5;
    }
    float (*tile)[33] = (float (*)[33])smem;
    const int c0 = bxt * 32, r0 = byt * 32;
    const int tx = tid & 31, ty = tid >> 5;   // 32 x 8
    #pragma unroll
    for (int k = 0; k < 32; k += 8)
      tile[ty + k][tx] = src[(size_t)(r0 + ty + k) * cols + c0 + tx];
    __syncthreads();
    #pragma unroll
    for (int k = 0; k < 32; k += 8)
      dst[(size_t)(c0 + ty + k) * rows + r0 + tx] = (_Float16)tile[tx][ty + k];
    __syncthreads();
  }
}

extern "C" void kernel_launch(void* const* d_in, const int* in_sizes, int n_in,
                              void* d_out, int out_size, void* d_ws, size_t ws_size,
                              hipStream_t stream) {
  const float* inter = (const float*)d_in[0];  // (B,S,H)
  const float* enr   = (const float*)d_in[1];  // (B,S,64)
  const float* convw = (const float*)d_in[2];  // (16,1,5,64)
  const float* convb = (const float*)d_in[3];  // (16,)
  const float* dproj = (const float*)d_in[4];  // (16,1024,128)
  const float* uproj = (const float*)d_in[5];  // (16,128,1024)
  float* out   = (float*)d_out;                // (B,S,H) fp32
  float* gates = out + (size_t)T_TOK * H_DIM;  // (B,S,16) fp32 = output 1

  // workspace: Xh(8MB) | BT1(4MB) | UT(4MB) | Dsc(16MB)
  _Float16* Xh  = (_Float16*)d_ws;
  _Float16* BT1 = Xh  + (size_t)T_TOK * H_DIM;
  _Float16* UT  = BT1 + (size_t)N1 * H_DIM;
  _Float16* Dsc = UT  + (size_t)H_DIM * N1;

  prep_kernel<<<8448, 256, 0, stream>>>(enr, convw, convb, inter, dproj, uproj,
                                        gates, Xh, BT1, UT);
  // GEMM1: Dsc[t, n*128+r] = gate[t,n] * sum_h X[t,h]*dproj[n,h,r]
  // 64x128 tile -> grid 1024, LDS 48KB -> 3 blocks/CU resident
  gemm_kernel<64, 128, 1, H_DIM, N1>
      <<<dim3(N1 / 128, T_TOK / 64), 256, 0, stream>>>(Xh, BT1, gates, (void*)Dsc);
  // GEMM2: out[t,h] = sum_nr Dsc[t,nr]*uproj[nr,h]
  // 64x64 tile -> grid 1024, LDS 32KB -> 4 blocks/CU resident
  gemm_kernel<64, 64, 0, N1, H_DIM>
      <<<dim3(H_DIM / 64, T_TOK / 64), 256, 0, stream>>>(Dsc, UT, nullptr, (void*)out);
}

// Round 8
// 138.141 us; speedup vs baseline: 1.0948x; 1.0948x over previous
//
#include <hip/hip_runtime.h>
#include <hip/hip_fp16.h>

// Problem constants (B,S,H,N_IN,N_PROC,R) = (4,1024,1024,64,16,128)
#define T_TOK 4096   // B*S tokens
#define H_DIM 1024
#define NIN   64
#define NP    16
#define R_DIM 128
#define S_DIM 1024
#define N1    (NP * R_DIM)   // 2048

typedef _Float16 half8  __attribute__((ext_vector_type(8)));
typedef _Float16 half4v __attribute__((ext_vector_type(4)));
typedef float    floatx16 __attribute__((ext_vector_type(16)));

typedef __attribute__((address_space(3))) unsigned char lds_u8_t;
typedef __attribute__((address_space(1))) unsigned char gbl_u8_t;

// async global->LDS, 16B/lane; LDS base must be wave-uniform (HW: base + lane*16)
__device__ __forceinline__ void g2l16(const void* g, void* l) {
  __builtin_amdgcn_global_load_lds((const gbl_u8_t*)g, (lds_u8_t*)l, 16, 0, 0);
}

// ---------------- MFMA GEMM: C(128x128/block) = A(MxK) * BT(NxK)^T ----------
// Double-buffered BK=64 K-loop, raw s_barrier + s_waitcnt vmcnt(8): next tile's
// DMA stays in flight across the barrier (hipBLASLt pattern); the wait covers
// only loads issued one full iteration earlier. LDS = 4 x 16KB = 64 KiB.
// LDS layout: 64 rows x 256B; row-pair packing (m and m+64 share a row, c_hi
// selects half) keeps the 16-chunk XOR-swizzle period (R6-verified 0 conflicts):
// element A[m][k0+kk] -> row m&63, logical chunk (kk>>3)+8*(m>>6), physical
// chunk = logical ^ (row&15). Waves 2x2, wave tile 64x64, 32x32x16 f16 MFMA.
template <int GATE, int K, int N>
__global__ __launch_bounds__(256)
void gemm_kernel(const _Float16* __restrict__ A, const _Float16* __restrict__ BT,
                 const float* __restrict__ gv, void* __restrict__ Cv) {
  constexpr int NK = K / 64;
  __shared__ __align__(16) _Float16 smem[4][64 * 128];  // A0 A1 B0 B1

  const int tid = threadIdx.x, wave = tid >> 6, lane = tid & 63;
  const int bxi = blockIdx.x;
  const int m0 = blockIdx.y * 128, n0 = bxi * 128;
  const int wr = (wave >> 1) * 64, wc = (wave & 1) * 64;
  const int rl = lane >> 4, ql = lane & 15;   // staging: row-in-call, chunk pos
  const int r = lane & 31, kh = lane >> 5;    // compute: mfma row, k-half

  // stage one 128x64 operand tile (16 KB) as 16 x 1KB DMA calls (4 per wave)
  auto stage = [&](const _Float16* __restrict__ base, int off0, int k0,
                   _Float16* dst) {
    #pragma unroll
    for (int c = 0; c < 4; ++c) {
      const int cc = wave * 4 + c;            // call id 0..15
      const int lrow = cc * 4 + rl;           // LDS row 0..63
      const int cl = ql ^ (lrow & 15);        // logical chunk this lane fetches
      const int row = lrow + ((cl >> 3) << 6);  // global row (row-pair unpack)
      g2l16(base + (size_t)(off0 + row) * K + k0 + (cl & 7) * 8, dst + cc * 512);
    }
  };

  floatx16 acc[2][2];
  #pragma unroll
  for (int i = 0; i < 2; ++i)
    #pragma unroll
    for (int j = 0; j < 2; ++j) acc[i][j] = (floatx16)0.f;

  _Float16 *cA = smem[0], *nA = smem[1], *cB = smem[2], *nB = smem[3];
  stage(A, m0, 0, cA);
  stage(BT, n0, 0, cB);

  #pragma unroll 2
  for (int k = 0; k < NK; ++k) {
    if (k + 1 < NK) {
      stage(A, m0, (k + 1) * 64, nA);
      stage(BT, n0, (k + 1) * 64, nB);
      __builtin_amdgcn_s_waitcnt(0xF78);   // vmcnt(8): prev tile landed, 8 in flight
    } else {
      __builtin_amdgcn_s_waitcnt(0xF70);   // vmcnt(0): final tile
    }
    __builtin_amdgcn_s_barrier();          // all waves' current-tile DMA visible
    __builtin_amdgcn_sched_barrier(0);
    #pragma unroll
    for (int h = 0; h < 4; ++h) {
      const int pA = (2 * h + kh + ((wave >> 1) << 3)) ^ (r & 15);
      const int pB = (2 * h + kh + ((wave & 1) << 3)) ^ (r & 15);
      half8 af[2], bf[2];
      #pragma unroll
      for (int i = 0; i < 2; ++i)
        af[i] = *reinterpret_cast<const half8*>(&cA[(i * 32 + r) * 128 + pA * 8]);
      #pragma unroll
      for (int j = 0; j < 2; ++j)
        bf[j] = *reinterpret_cast<const half8*>(&cB[(j * 32 + r) * 128 + pB * 8]);
      #pragma unroll
      for (int i = 0; i < 2; ++i)
        #pragma unroll
        for (int j = 0; j < 2; ++j)
          acc[i][j] = __builtin_amdgcn_mfma_f32_32x32x16_f16(af[i], bf[j], acc[i][j], 0, 0, 0);
    }
    __builtin_amdgcn_sched_barrier(0);
    __builtin_amdgcn_s_barrier();          // reads done; next iter may overwrite
    _Float16* t;
    t = cA; cA = nA; nA = t;
    t = cB; cB = nB; nB = t;
  }

  // 32x32 C/D layout: col = lane&31, row = (reg&3) + 8*(reg>>2) + 4*kh
  if (GATE) {
    _Float16* C = (_Float16*)Cv;   // BN==128 -> bxi == neuron n
    #pragma unroll
    for (int i = 0; i < 2; ++i)
      #pragma unroll
      for (int g4 = 0; g4 < 4; ++g4)
        #pragma unroll
        for (int rr = 0; rr < 4; ++rr) {
          const int rowL = wr + i * 32 + rr + 8 * g4 + 4 * kh;
          const float g = gv[(size_t)(m0 + rowL) * NP + bxi];  // L1-hot
          #pragma unroll
          for (int j = 0; j < 2; ++j)
            C[(size_t)(m0 + rowL) * N + n0 + wc + j * 32 + r] =
                (_Float16)(acc[i][j][g4 * 4 + rr] * g);
        }
  } else {
    float* C = (float*)Cv;
    #pragma unroll
    for (int i = 0; i < 2; ++i)
      #pragma unroll
      for (int g4 = 0; g4 < 4; ++g4)
        #pragma unroll
        for (int rr = 0; rr < 4; ++rr) {
          const int rowL = wr + i * 32 + rr + 8 * g4 + 4 * kh;
          #pragma unroll
          for (int j = 0; j < 2; ++j)
            C[(size_t)(m0 + rowL) * N + n0 + wc + j * 32 + r] = acc[i][j][g4 * 4 + rr];
        }
  }
}

// ---------------- prep: gates + cast + 2 transposes, ONE dispatch -----------
__global__ __launch_bounds__(256)
void prep_kernel(const float* __restrict__ enr, const float* __restrict__ cw,
                 const float* __restrict__ cb, const float* __restrict__ inter,
                 const float* __restrict__ dproj, const float* __restrict__ uproj,
                 float* __restrict__ gates, _Float16* __restrict__ Xh,
                 _Float16* __restrict__ BT1, _Float16* __restrict__ UT) {
  __shared__ __align__(16) char smem[25664];
  const int tid = threadIdx.x;
  const int bx = blockIdx.x, nb = gridDim.x;
  // ---- cast X fp32->fp16, grid-stride over 1M float4
  {
    const float4* src = (const float4*)inter;
    half4v* dst = (half4v*)Xh;
    for (int i = bx * 256 + tid; i < T_TOK * H_DIM / 4; i += nb * 256) {
      float4 v = src[i];
      half4v o;
      o[0] = (_Float16)v.x; o[1] = (_Float16)v.y; o[2] = (_Float16)v.z; o[3] = (_Float16)v.w;
      dst[i] = o;
    }
  }
  // ---- gates conv(k=5, 64ch mix)+sigmoid, blocks 0..255, 16 tokens each
  if (bx < 256) {
    float (*sw)[321] = (float (*)[321])smem;            // 20544 B
    float (*se)[NIN] = (float (*)[NIN])(smem + 20544);  //  5120 B
    const int t0 = bx * 16;
    const int b = t0 >> 10, s0 = t0 & 1023;   // 16 | S: no batch straddle
    for (int i = tid; i < NP * 320; i += 256) sw[i / 320][i % 320] = cw[i];
    for (int i = tid; i < 20 * NIN; i += 256) {
      int rr = i >> 6, c = i & 63, s = s0 + rr - 2;
      se[rr][c] = (s >= 0 && s < S_DIM) ? enr[((size_t)b * S_DIM + s) * NIN + c] : 0.f;
    }
    __syncthreads();
    const int lt = tid >> 4, n = tid & 15;
    float acc = cb[n];
    #pragma unroll
    for (int dh = 0; dh < 5; ++dh) {
      const float* wrow = &sw[n][dh * 64];
      const float* erow = se[lt + dh];
      #pragma unroll
      for (int j = 0; j < NIN; ++j) acc += erow[j] * wrow[j];
    }
    gates[(size_t)(t0 + lt) * NP + n] = 1.f / (1.f + expf(-acc));
    __syncthreads();   // LDS reused by transposes next
  }
  // ---- transpose+cast units (2048 dprojT + 2048 uprojT), strided over grid
  for (int u = bx; u < 4096; u += nb) {
    const float* src; _Float16* dst; int rows, cols, bxt, byt;
    if (u < 2048) {      // dproj[n] (1024x128) -> BT1 block n (128x1024)
      int n = u >> 7, rem = u & 127;
      src = dproj + (size_t)n * H_DIM * R_DIM;
      dst = BT1 + (size_t)n * R_DIM * H_DIM;
      rows = H_DIM; cols = R_DIM; bxt = rem & 3; byt = rem >> 2;
    } else {             // uproj (2048x1024) -> UT (1024x2048)
      int u2 = u - 2048;
      src = uproj; dst = UT; rows = N1; cols = H_DIM;
      bxt = u2 & 31; byt = u2 >> 5;
    }
    float (*tile)[33] = (float (*)[33])smem;
    const int c0 = bxt * 32, r0 = byt * 32;
    const int tx = tid & 31, ty = tid >> 5;   // 32 x 8
    #pragma unroll
    for (int k = 0; k < 32; k += 8)
      tile[ty + k][tx] = src[(size_t)(r0 + ty + k) * cols + c0 + tx];
    __syncthreads();
    #pragma unroll
    for (int k = 0; k < 32; k += 8)
      dst[(size_t)(c0 + ty + k) * rows + r0 + tx] = (_Float16)tile[tx][ty + k];
    __syncthreads();
  }
}

extern "C" void kernel_launch(void* const* d_in, const int* in_sizes, int n_in,
                              void* d_out, int out_size, void* d_ws, size_t ws_size,
                              hipStream_t stream) {
  const float* inter = (const float*)d_in[0];  // (B,S,H)
  const float* enr   = (const float*)d_in[1];  // (B,S,64)
  const float* convw = (const float*)d_in[2];  // (16,1,5,64)
  const float* convb = (const float*)d_in[3];  // (16,)
  const float* dproj = (const float*)d_in[4];  // (16,1024,128)
  const float* uproj = (const float*)d_in[5];  // (16,128,1024)
  float* out   = (float*)d_out;                // (B,S,H) fp32
  float* gates = out + (size_t)T_TOK * H_DIM;  // (B,S,16) fp32 = output 1

  // workspace: Xh(8MB) | BT1(4MB) | UT(4MB) | Dsc(16MB)
  _Float16* Xh  = (_Float16*)d_ws;
  _Float16* BT1 = Xh  + (size_t)T_TOK * H_DIM;
  _Float16* UT  = BT1 + (size_t)N1 * H_DIM;
  _Float16* Dsc = UT  + (size_t)H_DIM * N1;

  prep_kernel<<<8448, 256, 0, stream>>>(enr, convw, convb, inter, dproj, uproj,
                                        gates, Xh, BT1, UT);
  // GEMM1: Dsc[t, n*128+r] = gate[t,n] * sum_h X[t,h]*dproj[n,h,r]; 16x32 grid
  gemm_kernel<1, H_DIM, N1>
      <<<dim3(N1 / 128, T_TOK / 128), 256, 0, stream>>>(Xh, BT1, gates, (void*)Dsc);
  // GEMM2: out[t,h] = sum_nr Dsc[t,nr]*uproj[nr,h]; 8x32 grid
  gemm_kernel<0, N1, H_DIM>
      <<<dim3(H_DIM / 128, T_TOK / 128), 256, 0, stream>>>(Dsc, UT, nullptr, (void*)out);
}